// Round 1
// baseline (1064.711 us; speedup 1.0000x reference)
//
#include <hip/hip_runtime.h>
#include <math.h>

#define NN 100000
#define NE 1600000
#define DI 256
#define DH 64
#define DO 47

// ---------------- degree (int atomics, deterministic) ----------------
__global__ __launch_bounds__(256) void k_degree(const int* __restrict__ dst,
                                                int* __restrict__ deg) {
    int e = blockIdx.x * 256 + threadIdx.x;
    if (e < NE) atomicAdd(&deg[dst[e]], 1);
}

// ---------------- dinv = rsqrt(deg + 1 self-loop) ----------------
__global__ __launch_bounds__(256) void k_dinv(const int* __restrict__ deg,
                                              float* __restrict__ dinv) {
    int i = blockIdx.x * 256 + threadIdx.x;
    if (i < NN) dinv[i] = rsqrtf((float)(deg[i] + 1));
}

// ---------------- h1 = x @ W1  (N x 256 x 64) ----------------
// 4 waves/block, each wave owns 4 rows; lane = output column.
// W1 staged in LDS (64 KB). Register-block 4 rows per lane so each LDS read
// feeds 4 FMAs -> VALU-bound (~1.64G FMA lanes).
__global__ __launch_bounds__(256) void k_gemm1(const float* __restrict__ x,
                                               const float* __restrict__ W1,
                                               float* __restrict__ h1) {
    __shared__ float w[DI * DH];
    for (int i = threadIdx.x; i < DI * DH; i += 256) w[i] = W1[i];
    __syncthreads();
    const int wv = threadIdx.x >> 6, lane = threadIdx.x & 63;
    const int row0 = blockIdx.x * 16 + wv * 4;
    const float4* x0 = (const float4*)(x + (long)(row0 + 0) * DI);
    const float4* x1 = (const float4*)(x + (long)(row0 + 1) * DI);
    const float4* x2 = (const float4*)(x + (long)(row0 + 2) * DI);
    const float4* x3 = (const float4*)(x + (long)(row0 + 3) * DI);
    float a0 = 0.f, a1 = 0.f, a2 = 0.f, a3 = 0.f;
    #pragma unroll 4
    for (int k4 = 0; k4 < DI / 4; ++k4) {
        float4 v0 = x0[k4], v1 = x1[k4], v2 = x2[k4], v3 = x3[k4];
        const float* wp = &w[(k4 * 4) * DH + lane];
        float w0 = wp[0], w1b = wp[DH], w2b = wp[2 * DH], w3b = wp[3 * DH];
        a0 += v0.x * w0 + v0.y * w1b + v0.z * w2b + v0.w * w3b;
        a1 += v1.x * w0 + v1.y * w1b + v1.z * w2b + v1.w * w3b;
        a2 += v2.x * w0 + v2.y * w1b + v2.z * w2b + v2.w * w3b;
        a3 += v3.x * w0 + v3.y * w1b + v3.z * w2b + v3.w * w3b;
    }
    h1[(long)(row0 + 0) * DH + lane] = a0;
    h1[(long)(row0 + 1) * DH + lane] = a1;
    h1[(long)(row0 + 2) * DH + lane] = a2;
    h1[(long)(row0 + 3) * DH + lane] = a3;
}

// ---------------- scatter layer 1: agg1[dst] += norm * h1[src] ----------------
// one wave per edge, lane = feature column (64 = DH, perfect fit)
__global__ __launch_bounds__(256) void k_scatter1(const int* __restrict__ src,
                                                  const int* __restrict__ dst,
                                                  const float* __restrict__ dinv,
                                                  const float* __restrict__ h1,
                                                  float* __restrict__ agg1) {
    int e = blockIdx.x * 4 + (threadIdx.x >> 6);
    int lane = threadIdx.x & 63;
    if (e >= NE) return;
    int s = src[e], d = dst[e];
    float nrm = dinv[s] * dinv[d];
    atomicAdd(&agg1[(long)d * DH + lane], nrm * h1[(long)s * DH + lane]);
}

// ---------------- epilogue1 + GEMM2 ----------------
// h2 = relu(agg1 + dinv^2*h1 + b1); h3 = h2 @ W2 written IN PLACE into h1's
// row (stride 64, cols 0..46) — safe: each row read+written by exactly one wave.
__global__ __launch_bounds__(256) void k_epi1(float* __restrict__ h1,
                                              const float* __restrict__ agg1,
                                              const float* __restrict__ dinv,
                                              const float* __restrict__ b1,
                                              const float* __restrict__ W2) {
    __shared__ float w2[DH * DO];     // 12 KB
    __shared__ float sh[4][DH];
    for (int i = threadIdx.x; i < DH * DO; i += 256) w2[i] = W2[i];
    __syncthreads();
    int wv = threadIdx.x >> 6, lane = threadIdx.x & 63;
    int row = blockIdx.x * 4 + wv;
    float di = dinv[row];
    float v = agg1[(long)row * DH + lane] + di * di * h1[(long)row * DH + lane] + b1[lane];
    v = fmaxf(v, 0.f);
    sh[wv][lane] = v;
    float acc = 0.f;
    if (lane < DO) {
        #pragma unroll 8
        for (int k = 0; k < DH; ++k)
            acc += sh[wv][k] * w2[k * DO + lane];
        h1[(long)row * DH + lane] = acc;   // h3 stored at stride DH
    }
}

// ---------------- scatter layer 2: xo[dst] += norm * h3[src] ----------------
__global__ __launch_bounds__(256) void k_scatter2(const int* __restrict__ src,
                                                  const int* __restrict__ dst,
                                                  const float* __restrict__ dinv,
                                                  const float* __restrict__ h3, // stride DH
                                                  float* __restrict__ xo) {
    int e = blockIdx.x * 4 + (threadIdx.x >> 6);
    int lane = threadIdx.x & 63;
    if (e >= NE || lane >= DO) return;
    int s = src[e], d = dst[e];
    float nrm = dinv[s] * dinv[d];
    atomicAdd(&xo[(long)d * DO + lane], nrm * h3[(long)s * DH + lane]);
}

// ---------------- epilogue2: self-loop + bias, softmax, argmax ----------------
__global__ __launch_bounds__(256) void k_epi2(float* __restrict__ xo,       // accum in, final out
                                              const float* __restrict__ h3, // stride DH
                                              const float* __restrict__ dinv,
                                              const float* __restrict__ b2,
                                              float* __restrict__ logits,
                                              float* __restrict__ preds) {
    int wv = threadIdx.x >> 6, lane = threadIdx.x & 63;
    int row = blockIdx.x * 4 + wv;
    float di = dinv[row];
    float val = -INFINITY;
    if (lane < DO) {
        val = xo[(long)row * DO + lane] + di * di * h3[(long)row * DH + lane] + b2[lane];
        xo[(long)row * DO + lane] = val;          // final xo (output 2)
    }
    // max reduce over 64 lanes
    float m = val;
    for (int off = 32; off; off >>= 1) m = fmaxf(m, __shfl_xor(m, off));
    // first-index argmax (matches jnp.argmax tie-break)
    int idx = (lane < DO && val == m) ? lane : (1 << 30);
    for (int off = 32; off; off >>= 1) idx = min(idx, __shfl_xor(idx, off));
    float ev = (lane < DO) ? expf(val - m) : 0.f;
    float ssum = ev;
    for (int off = 32; off; off >>= 1) ssum += __shfl_xor(ssum, off);
    if (lane < DO) logits[(long)row * DO + lane] = ev / ssum;
    if (lane == 0) preds[row] = (float)idx;       // whole d_out is read as f32
}

extern "C" void kernel_launch(void* const* d_in, const int* in_sizes, int n_in,
                              void* d_out, int out_size, void* d_ws, size_t ws_size,
                              hipStream_t stream) {
    const float* x  = (const float*)d_in[0];
    const int*   ei = (const int*)d_in[1];
    const float* W1 = (const float*)d_in[2];
    const float* b1 = (const float*)d_in[3];
    const float* W2 = (const float*)d_in[4];
    const float* b2 = (const float*)d_in[5];
    const int* src = ei;          // edge_index[0]
    const int* dst = ei + NE;     // edge_index[1]

    float* out    = (float*)d_out;
    float* logits = out;                      // [N,47]
    float* preds  = out + (long)NN * DO;      // [N]
    float* xo     = preds + NN;               // [N,47]

    float* ws   = (float*)d_ws;
    int*   deg  = (int*)d_ws;                 // N ints
    float* dinv = ws + NN;                    // N floats
    float* h1   = ws + 2L * NN;               // N*64 (reused as h3, stride 64)
    float* agg1 = h1 + (long)NN * DH;         // N*64
    // total ws use: 130*N floats = 52 MB

    hipMemsetAsync(deg, 0, NN * sizeof(int), stream);
    hipMemsetAsync(agg1, 0, (size_t)NN * DH * sizeof(float), stream);
    hipMemsetAsync(xo, 0, (size_t)NN * DO * sizeof(float), stream);

    k_degree<<<(NE + 255) / 256, 256, 0, stream>>>(dst, deg);
    k_dinv<<<(NN + 255) / 256, 256, 0, stream>>>(deg, dinv);
    k_gemm1<<<NN / 16, 256, 0, stream>>>(x, W1, h1);
    k_scatter1<<<NE / 4, 256, 0, stream>>>(src, dst, dinv, h1, agg1);
    k_epi1<<<NN / 4, 256, 0, stream>>>(h1, agg1, dinv, b1, W2);
    k_scatter2<<<NE / 4, 256, 0, stream>>>(src, dst, dinv, h1, xo);
    k_epi2<<<NN / 4, 256, 0, stream>>>(xo, h1, dinv, b2, logits, preds);
}

// Round 2
// 638.425 us; speedup vs baseline: 1.6677x; 1.6677x over previous
//
#include <hip/hip_runtime.h>
#include <math.h>

#define NN 100000
#define NE 1600000
#define DI 256
#define DH 64
#define DO 47
#define DH3 48                      // h3 row stride: 192B = 3 full cache lines
#define NB ((NN + 255) / 256)       // 391 scan blocks

// ---------------- degree (int atomics, deterministic) ----------------
__global__ __launch_bounds__(256) void k_degree(const int* __restrict__ dst,
                                                int* __restrict__ deg) {
    int e = blockIdx.x * 256 + threadIdx.x;
    if (e < NE) atomicAdd(&deg[dst[e]], 1);
}

__global__ __launch_bounds__(256) void k_dinv(const int* __restrict__ deg,
                                              float* __restrict__ dinv) {
    int i = blockIdx.x * 256 + threadIdx.x;
    if (i < NN) dinv[i] = rsqrtf((float)(deg[i] + 1));
}

// ---------------- scan pass 1: per-block sums of deg ----------------
__global__ __launch_bounds__(256) void k_part(const int* __restrict__ deg,
                                              int* __restrict__ part) {
    int i = blockIdx.x * 256 + threadIdx.x;
    int v = (i < NN) ? deg[i] : 0;
    for (int off = 32; off; off >>= 1) v += __shfl_xor(v, off);
    __shared__ int s[4];
    if ((threadIdx.x & 63) == 0) s[threadIdx.x >> 6] = v;
    __syncthreads();
    if (threadIdx.x == 0) part[blockIdx.x] = s[0] + s[1] + s[2] + s[3];
}

// ---------------- scan pass 2: exclusive scan of partials (NB<=512) ----------------
__global__ __launch_bounds__(512) void k_scanpart(int* __restrict__ part) {
    int t = threadIdx.x, lane = t & 63, wv = t >> 6;
    int v0 = (t < NB) ? part[t] : 0;
    int v = v0;
    for (int off = 1; off < 64; off <<= 1) {
        int u = __shfl_up(v, off);
        if (lane >= off) v += u;
    }
    __shared__ int ws[8];
    if (lane == 63) ws[wv] = v;
    __syncthreads();
    if (t == 0) {
        int run = 0;
        for (int w = 0; w < 8; ++w) { int tmp = ws[w]; ws[w] = run; run += tmp; }
    }
    __syncthreads();
    v += ws[wv];
    if (t < NB) part[t] = v - v0;   // exclusive
}

// ---------------- scan pass 3: per-element exclusive prefix -> rowptr, cursor ----------------
__global__ __launch_bounds__(256) void k_scan3(const int* __restrict__ deg,
                                               const int* __restrict__ part,
                                               int* __restrict__ rowptr,
                                               int* __restrict__ cursor) {
    int i = blockIdx.x * 256 + threadIdx.x;
    int lane = threadIdx.x & 63, wv = threadIdx.x >> 6;
    int v0 = (i < NN) ? deg[i] : 0;
    int v = v0;
    for (int off = 1; off < 64; off <<= 1) {
        int u = __shfl_up(v, off);
        if (lane >= off) v += u;
    }
    __shared__ int ws[4], wo[4];
    if (lane == 63) ws[wv] = v;
    __syncthreads();
    if (threadIdx.x == 0) {
        int run = 0;
        for (int w = 0; w < 4; ++w) { int tmp = ws[w]; wo[w] = run; run += tmp; }
    }
    __syncthreads();
    int excl = part[blockIdx.x] + wo[wv] + v - v0;
    if (i < NN) { rowptr[i] = excl; cursor[i] = excl; }
}

// ---------------- bucket-fill: csr_src[cursor[dst]++] = src ----------------
__global__ __launch_bounds__(256) void k_fill(const int* __restrict__ src,
                                              const int* __restrict__ dst,
                                              int* __restrict__ cursor,
                                              int* __restrict__ csr_src) {
    int e = blockIdx.x * 256 + threadIdx.x;
    if (e < NE) {
        int p = atomicAdd(&cursor[dst[e]], 1);
        csr_src[p] = src[e];
    }
}

// ---------------- h1 = x @ W1  (N x 256 x 64) ----------------
__global__ __launch_bounds__(256) void k_gemm1(const float* __restrict__ x,
                                               const float* __restrict__ W1,
                                               float* __restrict__ h1) {
    __shared__ float w[DI * DH];
    for (int i = threadIdx.x; i < DI * DH; i += 256) w[i] = W1[i];
    __syncthreads();
    const int wv = threadIdx.x >> 6, lane = threadIdx.x & 63;
    const int row0 = blockIdx.x * 16 + wv * 4;
    const float4* x0 = (const float4*)(x + (long)(row0 + 0) * DI);
    const float4* x1 = (const float4*)(x + (long)(row0 + 1) * DI);
    const float4* x2 = (const float4*)(x + (long)(row0 + 2) * DI);
    const float4* x3 = (const float4*)(x + (long)(row0 + 3) * DI);
    float a0 = 0.f, a1 = 0.f, a2 = 0.f, a3 = 0.f;
    #pragma unroll 4
    for (int k4 = 0; k4 < DI / 4; ++k4) {
        float4 v0 = x0[k4], v1 = x1[k4], v2 = x2[k4], v3 = x3[k4];
        const float* wp = &w[(k4 * 4) * DH + lane];
        float w0 = wp[0], w1b = wp[DH], w2b = wp[2 * DH], w3b = wp[3 * DH];
        a0 += v0.x * w0 + v0.y * w1b + v0.z * w2b + v0.w * w3b;
        a1 += v1.x * w0 + v1.y * w1b + v1.z * w2b + v1.w * w3b;
        a2 += v2.x * w0 + v2.y * w1b + v2.z * w2b + v2.w * w3b;
        a3 += v3.x * w0 + v3.y * w1b + v3.z * w2b + v3.w * w3b;
    }
    h1[(long)(row0 + 0) * DH + lane] = a0;
    h1[(long)(row0 + 1) * DH + lane] = a1;
    h1[(long)(row0 + 2) * DH + lane] = a2;
    h1[(long)(row0 + 3) * DH + lane] = a3;
}

// ---------------- layer1 gather + relu/bias + GEMM2 fused ----------------
// agg = dinv[d] * (sum_s dinv[s]*h1[s] + dinv[d]*h1[d]); h2=relu(agg+b1);
// h3 = h2 @ W2 -> separate buffer, row stride DH3.
__global__ __launch_bounds__(256) void k_agg1(const int* __restrict__ rowptr,
                                              const int* __restrict__ deg,
                                              const int* __restrict__ csr_src,
                                              const float* __restrict__ dinv,
                                              const float* __restrict__ h1,
                                              const float* __restrict__ b1,
                                              const float* __restrict__ W2,
                                              float* __restrict__ h3) {
    __shared__ float w2[DH * DO];   // 12 KB
    __shared__ float sh[4][DH];
    for (int i = threadIdx.x; i < DH * DO; i += 256) w2[i] = W2[i];
    __syncthreads();
    int wv = threadIdx.x >> 6, lane = threadIdx.x & 63;
    int row = blockIdx.x * 4 + wv;   // NN % 4 == 0, always valid
    int beg = rowptr[row], cnt = deg[row];
    float acc = 0.f;
    int j = 0;
    for (; j + 3 < cnt; j += 4) {
        int s0 = csr_src[beg + j], s1 = csr_src[beg + j + 1];
        int s2 = csr_src[beg + j + 2], s3 = csr_src[beg + j + 3];
        float d0 = dinv[s0], d1 = dinv[s1], d2 = dinv[s2], d3 = dinv[s3];
        float v0 = h1[(long)s0 * DH + lane], v1 = h1[(long)s1 * DH + lane];
        float v2 = h1[(long)s2 * DH + lane], v3 = h1[(long)s3 * DH + lane];
        acc += d0 * v0 + d1 * v1 + d2 * v2 + d3 * v3;
    }
    for (; j < cnt; ++j) {
        int s = csr_src[beg + j];
        acc += dinv[s] * h1[(long)s * DH + lane];
    }
    float di = dinv[row];
    float v = di * (acc + di * h1[(long)row * DH + lane]) + b1[lane];
    sh[wv][lane] = fmaxf(v, 0.f);
    __syncthreads();
    if (lane < DO) {
        float o = 0.f;
        #pragma unroll 8
        for (int k = 0; k < DH; ++k)
            o += sh[wv][k] * w2[k * DO + lane];
        h3[(long)row * DH3 + lane] = o;
    }
}

// ---------------- layer2 gather + self-loop/bias + softmax/argmax fused ----------------
__global__ __launch_bounds__(256) void k_agg2(const int* __restrict__ rowptr,
                                              const int* __restrict__ deg,
                                              const int* __restrict__ csr_src,
                                              const float* __restrict__ dinv,
                                              const float* __restrict__ h3,
                                              const float* __restrict__ b2,
                                              float* __restrict__ logits,
                                              float* __restrict__ preds,
                                              float* __restrict__ xo) {
    int wv = threadIdx.x >> 6, lane = threadIdx.x & 63;
    int row = blockIdx.x * 4 + wv;
    int beg = rowptr[row], cnt = deg[row];
    float acc = 0.f;
    int j = 0;
    for (; j + 3 < cnt; j += 4) {
        int s0 = csr_src[beg + j], s1 = csr_src[beg + j + 1];
        int s2 = csr_src[beg + j + 2], s3 = csr_src[beg + j + 3];
        float d0 = dinv[s0], d1 = dinv[s1], d2 = dinv[s2], d3 = dinv[s3];
        if (lane < DO) {
            acc += d0 * h3[(long)s0 * DH3 + lane] + d1 * h3[(long)s1 * DH3 + lane]
                 + d2 * h3[(long)s2 * DH3 + lane] + d3 * h3[(long)s3 * DH3 + lane];
        }
    }
    for (; j < cnt; ++j) {
        int s = csr_src[beg + j];
        float d = dinv[s];
        if (lane < DO) acc += d * h3[(long)s * DH3 + lane];
    }
    float di = dinv[row];
    float val = -INFINITY;
    if (lane < DO) {
        val = di * (acc + di * h3[(long)row * DH3 + lane]) + b2[lane];
        xo[(long)row * DO + lane] = val;
    }
    float m = val;
    for (int off = 32; off; off >>= 1) m = fmaxf(m, __shfl_xor(m, off));
    int idx = (lane < DO && val == m) ? lane : (1 << 30);
    for (int off = 32; off; off >>= 1) idx = min(idx, __shfl_xor(idx, off));
    float ev = (lane < DO) ? expf(val - m) : 0.f;
    float ssum = ev;
    for (int off = 32; off; off >>= 1) ssum += __shfl_xor(ssum, off);
    if (lane < DO) logits[(long)row * DO + lane] = ev / ssum;
    if (lane == 0) preds[row] = (float)idx;
}

extern "C" void kernel_launch(void* const* d_in, const int* in_sizes, int n_in,
                              void* d_out, int out_size, void* d_ws, size_t ws_size,
                              hipStream_t stream) {
    const float* x  = (const float*)d_in[0];
    const int*   ei = (const int*)d_in[1];
    const float* W1 = (const float*)d_in[2];
    const float* b1 = (const float*)d_in[3];
    const float* W2 = (const float*)d_in[4];
    const float* b2 = (const float*)d_in[5];
    const int* src = ei;          // edge_index[0]
    const int* dst = ei + NE;     // edge_index[1]

    float* out    = (float*)d_out;
    float* logits = out;                      // [N,47]
    float* preds  = out + (long)NN * DO;      // [N]
    float* xo     = preds + NN;               // [N,47]

    // workspace layout (floats/ints, 4B units)
    char* wsb = (char*)d_ws;
    int*   deg     = (int*)wsb;                         wsb += (size_t)NN * 4;
    float* dinv    = (float*)wsb;                       wsb += (size_t)NN * 4;
    int*   rowptr  = (int*)wsb;                         wsb += (size_t)NN * 4;
    int*   cursor  = (int*)wsb;                         wsb += (size_t)NN * 4;
    int*   part    = (int*)wsb;                         wsb += (size_t)512 * 4;
    int*   csr_src = (int*)wsb;                         wsb += (size_t)NE * 4;
    float* h1      = (float*)wsb;                       wsb += (size_t)NN * DH * 4;
    float* h3      = (float*)wsb;                       wsb += (size_t)NN * DH3 * 4;
    // total ~52.8 MB

    hipMemsetAsync(deg, 0, NN * sizeof(int), stream);

    k_degree<<<(NE + 255) / 256, 256, 0, stream>>>(dst, deg);
    k_dinv<<<(NN + 255) / 256, 256, 0, stream>>>(deg, dinv);
    k_part<<<NB, 256, 0, stream>>>(deg, part);
    k_scanpart<<<1, 512, 0, stream>>>(part);
    k_scan3<<<NB, 256, 0, stream>>>(deg, part, rowptr, cursor);
    k_fill<<<(NE + 255) / 256, 256, 0, stream>>>(src, dst, cursor, csr_src);
    k_gemm1<<<NN / 16, 256, 0, stream>>>(x, W1, h1);
    k_agg1<<<NN / 4, 256, 0, stream>>>(rowptr, deg, csr_src, dinv, h1, b1, W2, h3);
    k_agg2<<<NN / 4, 256, 0, stream>>>(rowptr, deg, csr_src, dinv, h3, b2, logits, preds, xo);
}

// Round 3
// 465.545 us; speedup vs baseline: 2.2870x; 1.3713x over previous
//
#include <hip/hip_runtime.h>
#include <math.h>

#define NN 100000
#define NE 1600000
#define DI 256
#define DH 64
#define DO 47
#define DH3 48                      // h3 row stride: 192B = 3 full cache lines
#define NB ((NN + 255) / 256)       // 391 scan blocks

typedef float f8 __attribute__((ext_vector_type(8)));

// ---------------- degree (int atomics, deterministic) ----------------
__global__ __launch_bounds__(256) void k_degree(const int* __restrict__ dst,
                                                int* __restrict__ deg) {
    int e = blockIdx.x * 256 + threadIdx.x;
    if (e < NE) atomicAdd(&deg[dst[e]], 1);
}

__global__ __launch_bounds__(256) void k_dinv(const int* __restrict__ deg,
                                              float* __restrict__ dinv) {
    int i = blockIdx.x * 256 + threadIdx.x;
    if (i < NN) dinv[i] = rsqrtf((float)(deg[i] + 1));
}

// ---------------- scan pass 1: per-block sums of deg ----------------
__global__ __launch_bounds__(256) void k_part(const int* __restrict__ deg,
                                              int* __restrict__ part) {
    int i = blockIdx.x * 256 + threadIdx.x;
    int v = (i < NN) ? deg[i] : 0;
    for (int off = 32; off; off >>= 1) v += __shfl_xor(v, off);
    __shared__ int s[4];
    if ((threadIdx.x & 63) == 0) s[threadIdx.x >> 6] = v;
    __syncthreads();
    if (threadIdx.x == 0) part[blockIdx.x] = s[0] + s[1] + s[2] + s[3];
}

// ---------------- scan pass 2: exclusive scan of partials (NB<=512) ----------------
__global__ __launch_bounds__(512) void k_scanpart(int* __restrict__ part) {
    int t = threadIdx.x, lane = t & 63, wv = t >> 6;
    int v0 = (t < NB) ? part[t] : 0;
    int v = v0;
    for (int off = 1; off < 64; off <<= 1) {
        int u = __shfl_up(v, off);
        if (lane >= off) v += u;
    }
    __shared__ int ws[8];
    if (lane == 63) ws[wv] = v;
    __syncthreads();
    if (t == 0) {
        int run = 0;
        for (int w = 0; w < 8; ++w) { int tmp = ws[w]; ws[w] = run; run += tmp; }
    }
    __syncthreads();
    v += ws[wv];
    if (t < NB) part[t] = v - v0;   // exclusive
}

// ---------------- scan pass 3: per-element exclusive prefix -> rowptr, cursor ----------------
__global__ __launch_bounds__(256) void k_scan3(const int* __restrict__ deg,
                                               const int* __restrict__ part,
                                               int* __restrict__ rowptr,
                                               int* __restrict__ cursor) {
    int i = blockIdx.x * 256 + threadIdx.x;
    int lane = threadIdx.x & 63, wv = threadIdx.x >> 6;
    int v0 = (i < NN) ? deg[i] : 0;
    int v = v0;
    for (int off = 1; off < 64; off <<= 1) {
        int u = __shfl_up(v, off);
        if (lane >= off) v += u;
    }
    __shared__ int ws[4], wo[4];
    if (lane == 63) ws[wv] = v;
    __syncthreads();
    if (threadIdx.x == 0) {
        int run = 0;
        for (int w = 0; w < 4; ++w) { int tmp = ws[w]; wo[w] = run; run += tmp; }
    }
    __syncthreads();
    int excl = part[blockIdx.x] + wo[wv] + v - v0;
    if (i < NN) { rowptr[i] = excl; cursor[i] = excl; }
}

// ---------------- bucket-fill: csr_src[cursor[dst]++] = src ----------------
__global__ __launch_bounds__(256) void k_fill(const int* __restrict__ src,
                                              const int* __restrict__ dst,
                                              int* __restrict__ cursor,
                                              int* __restrict__ csr_src) {
    int e = blockIdx.x * 256 + threadIdx.x;
    if (e < NE) {
        int p = atomicAdd(&cursor[dst[e]], 1);
        csr_src[p] = src[e];
    }
}

// ---------------- h1 = x @ W1  (N x 256 x 64) ----------------
// Block = 512 threads (8 waves), 64 rows/block, lane = row.
// Wave w owns output cols [8w, 8w+8); 8 accumulators per lane.
// x streamed via small double-buffered LDS tile [64][17] (stride 17 -> <=2-way
// bank aliasing = free). W1 row-slices are wave-uniform -> scalar loads
// (readfirstlane-forced), consumed as the SGPR operand of v_fmac.
// LDS 8.7 KB, VGPR ~40 -> 32 waves/CU occupancy (vs 8 before).
__global__ __launch_bounds__(512) void k_gemm1(const float* __restrict__ x,
                                               const float* __restrict__ W1,
                                               float* __restrict__ h1) {
    __shared__ float xs[2][64 * 17];
    const int t = threadIdx.x;
    const int lane = t & 63;
    const int wvu = __builtin_amdgcn_readfirstlane(t >> 6);  // uniform wave id
    const int r0 = blockIdx.x * 64;
    // staging: thread t loads float2 of row (t>>3), k-offset 2*(t&7)
    const int sr = t >> 3;
    const int sk = (t & 7) * 2;
    const long xrow = (long)min(r0 + sr, NN - 1) * DI;
    const int row = r0 + lane;

    float acc[8] = {0.f, 0.f, 0.f, 0.f, 0.f, 0.f, 0.f, 0.f};

    {   // stage chunk 0
        float2 v = *(const float2*)(x + xrow + sk);
        xs[0][sr * 17 + sk] = v.x;
        xs[0][sr * 17 + sk + 1] = v.y;
    }
    __syncthreads();
    for (int c = 0; c < 16; ++c) {
        const int buf = c & 1;
        if (c + 1 < 16) {   // prefetch next chunk into other buffer
            float2 v = *(const float2*)(x + xrow + (c + 1) * 16 + sk);
            xs[buf ^ 1][sr * 17 + sk] = v.x;
            xs[buf ^ 1][sr * 17 + sk + 1] = v.y;
        }
        // W1 rows c*16..c*16+15, col block wvu: uniform address -> s_load
        const f8* wp = (const f8*)(W1) + (size_t)(c * 16) * (DH / 8) + wvu;
        #pragma unroll
        for (int k = 0; k < 16; ++k) {
            float xv = xs[buf][lane * 17 + k];
            f8 w8 = wp[(size_t)k * (DH / 8)];
            #pragma unroll
            for (int j = 0; j < 8; ++j) acc[j] += w8[j] * xv;
        }
        __syncthreads();
    }
    if (row < NN) {
        float4 o0 = {acc[0], acc[1], acc[2], acc[3]};
        float4 o1 = {acc[4], acc[5], acc[6], acc[7]};
        float4* hp = (float4*)(h1 + (long)row * DH + wvu * 8);
        hp[0] = o0;
        hp[1] = o1;
    }
}

// ---------------- layer1 gather + relu/bias + GEMM2 fused ----------------
__global__ __launch_bounds__(256) void k_agg1(const int* __restrict__ rowptr,
                                              const int* __restrict__ deg,
                                              const int* __restrict__ csr_src,
                                              const float* __restrict__ dinv,
                                              const float* __restrict__ h1,
                                              const float* __restrict__ b1,
                                              const float* __restrict__ W2,
                                              float* __restrict__ h3) {
    __shared__ float w2[DH * DO];   // 12 KB
    __shared__ float sh[4][DH];
    for (int i = threadIdx.x; i < DH * DO; i += 256) w2[i] = W2[i];
    __syncthreads();
    int wv = threadIdx.x >> 6, lane = threadIdx.x & 63;
    int row = blockIdx.x * 4 + wv;   // NN % 4 == 0, always valid
    int beg = rowptr[row], cnt = deg[row];
    float acc = 0.f;
    int j = 0;
    for (; j + 3 < cnt; j += 4) {
        int s0 = csr_src[beg + j], s1 = csr_src[beg + j + 1];
        int s2 = csr_src[beg + j + 2], s3 = csr_src[beg + j + 3];
        float d0 = dinv[s0], d1 = dinv[s1], d2 = dinv[s2], d3 = dinv[s3];
        float v0 = h1[(long)s0 * DH + lane], v1 = h1[(long)s1 * DH + lane];
        float v2 = h1[(long)s2 * DH + lane], v3 = h1[(long)s3 * DH + lane];
        acc += d0 * v0 + d1 * v1 + d2 * v2 + d3 * v3;
    }
    for (; j < cnt; ++j) {
        int s = csr_src[beg + j];
        acc += dinv[s] * h1[(long)s * DH + lane];
    }
    float di = dinv[row];
    float v = di * (acc + di * h1[(long)row * DH + lane]) + b1[lane];
    sh[wv][lane] = fmaxf(v, 0.f);
    __syncthreads();
    if (lane < DO) {
        float o = 0.f;
        #pragma unroll 8
        for (int k = 0; k < DH; ++k)
            o += sh[wv][k] * w2[k * DO + lane];
        h3[(long)row * DH3 + lane] = o;
    }
}

// ---------------- layer2 gather + self-loop/bias + softmax/argmax fused ----------------
__global__ __launch_bounds__(256) void k_agg2(const int* __restrict__ rowptr,
                                              const int* __restrict__ deg,
                                              const int* __restrict__ csr_src,
                                              const float* __restrict__ dinv,
                                              const float* __restrict__ h3,
                                              const float* __restrict__ b2,
                                              float* __restrict__ logits,
                                              float* __restrict__ preds,
                                              float* __restrict__ xo) {
    int wv = threadIdx.x >> 6, lane = threadIdx.x & 63;
    int row = blockIdx.x * 4 + wv;
    int beg = rowptr[row], cnt = deg[row];
    float acc = 0.f;
    int j = 0;
    for (; j + 3 < cnt; j += 4) {
        int s0 = csr_src[beg + j], s1 = csr_src[beg + j + 1];
        int s2 = csr_src[beg + j + 2], s3 = csr_src[beg + j + 3];
        float d0 = dinv[s0], d1 = dinv[s1], d2 = dinv[s2], d3 = dinv[s3];
        if (lane < DO) {
            acc += d0 * h3[(long)s0 * DH3 + lane] + d1 * h3[(long)s1 * DH3 + lane]
                 + d2 * h3[(long)s2 * DH3 + lane] + d3 * h3[(long)s3 * DH3 + lane];
        }
    }
    for (; j < cnt; ++j) {
        int s = csr_src[beg + j];
        float d = dinv[s];
        if (lane < DO) acc += d * h3[(long)s * DH3 + lane];
    }
    float di = dinv[row];
    float val = -INFINITY;
    if (lane < DO) {
        val = di * (acc + di * h3[(long)row * DH3 + lane]) + b2[lane];
        xo[(long)row * DO + lane] = val;
    }
    float m = val;
    for (int off = 32; off; off >>= 1) m = fmaxf(m, __shfl_xor(m, off));
    int idx = (lane < DO && val == m) ? lane : (1 << 30);
    for (int off = 32; off; off >>= 1) idx = min(idx, __shfl_xor(idx, off));
    float ev = (lane < DO) ? expf(val - m) : 0.f;
    float ssum = ev;
    for (int off = 32; off; off >>= 1) ssum += __shfl_xor(ssum, off);
    if (lane < DO) logits[(long)row * DO + lane] = ev / ssum;
    if (lane == 0) preds[row] = (float)idx;
}

extern "C" void kernel_launch(void* const* d_in, const int* in_sizes, int n_in,
                              void* d_out, int out_size, void* d_ws, size_t ws_size,
                              hipStream_t stream) {
    const float* x  = (const float*)d_in[0];
    const int*   ei = (const int*)d_in[1];
    const float* W1 = (const float*)d_in[2];
    const float* b1 = (const float*)d_in[3];
    const float* W2 = (const float*)d_in[4];
    const float* b2 = (const float*)d_in[5];
    const int* src = ei;          // edge_index[0]
    const int* dst = ei + NE;     // edge_index[1]

    float* out    = (float*)d_out;
    float* logits = out;                      // [N,47]
    float* preds  = out + (long)NN * DO;      // [N]
    float* xo     = preds + NN;               // [N,47]

    // workspace layout
    char* wsb = (char*)d_ws;
    int*   deg     = (int*)wsb;                         wsb += (size_t)NN * 4;
    float* dinv    = (float*)wsb;                       wsb += (size_t)NN * 4;
    int*   rowptr  = (int*)wsb;                         wsb += (size_t)NN * 4;
    int*   cursor  = (int*)wsb;                         wsb += (size_t)NN * 4;
    int*   part    = (int*)wsb;                         wsb += (size_t)512 * 4;
    int*   csr_src = (int*)wsb;                         wsb += (size_t)NE * 4;
    float* h1      = (float*)wsb;                       wsb += (size_t)NN * DH * 4;
    float* h3      = (float*)wsb;                       wsb += (size_t)NN * DH3 * 4;

    hipMemsetAsync(deg, 0, NN * sizeof(int), stream);

    k_degree<<<(NE + 255) / 256, 256, 0, stream>>>(dst, deg);
    k_dinv<<<(NN + 255) / 256, 256, 0, stream>>>(deg, dinv);
    k_part<<<NB, 256, 0, stream>>>(deg, part);
    k_scanpart<<<1, 512, 0, stream>>>(part);
    k_scan3<<<NB, 256, 0, stream>>>(deg, part, rowptr, cursor);
    k_fill<<<(NE + 255) / 256, 256, 0, stream>>>(src, dst, cursor, csr_src);
    k_gemm1<<<(NN + 63) / 64, 512, 0, stream>>>(x, W1, h1);
    k_agg1<<<NN / 4, 256, 0, stream>>>(rowptr, deg, csr_src, dinv, h1, b1, W2, h3);
    k_agg2<<<NN / 4, 256, 0, stream>>>(rowptr, deg, csr_src, dinv, h3, b2, logits, preds, xo);
}

// Round 4
// 426.382 us; speedup vs baseline: 2.4971x; 1.0919x over previous
//
#include <hip/hip_runtime.h>
#include <math.h>

#define NN 100000
#define NE 1600000
#define DI 256
#define DH 64
#define DO 47
#define DH3 48                      // h3 row stride: 192B = 3 full cache lines
#define NB ((NN + 255) / 256)       // 391 scan blocks
#define NRANGE 8                    // dst ranges for locality-phased fill
#define RSZ ((NN + NRANGE - 1) / NRANGE)      // 12500 nodes per range
#define EPB 2048                    // edges per fill block
#define CPB ((NE + EPB - 1) / EPB)  // 782 chunks per range

typedef float f8 __attribute__((ext_vector_type(8)));

// ---------------- degree (int atomics, deterministic) ----------------
__global__ __launch_bounds__(256) void k_degree(const int* __restrict__ dst,
                                                int* __restrict__ deg) {
    int e = blockIdx.x * 256 + threadIdx.x;
    if (e < NE) atomicAdd(&deg[dst[e]], 1);
}

__global__ __launch_bounds__(256) void k_dinv(const int* __restrict__ deg,
                                              float* __restrict__ dinv) {
    int i = blockIdx.x * 256 + threadIdx.x;
    if (i < NN) dinv[i] = rsqrtf((float)(deg[i] + 1));
}

// ---------------- scan pass 1: per-block sums of deg ----------------
__global__ __launch_bounds__(256) void k_part(const int* __restrict__ deg,
                                              int* __restrict__ part) {
    int i = blockIdx.x * 256 + threadIdx.x;
    int v = (i < NN) ? deg[i] : 0;
    for (int off = 32; off; off >>= 1) v += __shfl_xor(v, off);
    __shared__ int s[4];
    if ((threadIdx.x & 63) == 0) s[threadIdx.x >> 6] = v;
    __syncthreads();
    if (threadIdx.x == 0) part[blockIdx.x] = s[0] + s[1] + s[2] + s[3];
}

// ---------------- scan pass 2: exclusive scan of partials (NB<=512) ----------------
__global__ __launch_bounds__(512) void k_scanpart(int* __restrict__ part) {
    int t = threadIdx.x, lane = t & 63, wv = t >> 6;
    int v0 = (t < NB) ? part[t] : 0;
    int v = v0;
    for (int off = 1; off < 64; off <<= 1) {
        int u = __shfl_up(v, off);
        if (lane >= off) v += u;
    }
    __shared__ int ws[8];
    if (lane == 63) ws[wv] = v;
    __syncthreads();
    if (t == 0) {
        int run = 0;
        for (int w = 0; w < 8; ++w) { int tmp = ws[w]; ws[w] = run; run += tmp; }
    }
    __syncthreads();
    v += ws[wv];
    if (t < NB) part[t] = v - v0;   // exclusive
}

// ---------------- scan pass 3: per-element exclusive prefix -> rowptr, cursor ----------------
__global__ __launch_bounds__(256) void k_scan3(const int* __restrict__ deg,
                                               const int* __restrict__ part,
                                               int* __restrict__ rowptr,
                                               int* __restrict__ cursor) {
    int i = blockIdx.x * 256 + threadIdx.x;
    int lane = threadIdx.x & 63, wv = threadIdx.x >> 6;
    int v0 = (i < NN) ? deg[i] : 0;
    int v = v0;
    for (int off = 1; off < 64; off <<= 1) {
        int u = __shfl_up(v, off);
        if (lane >= off) v += u;
    }
    __shared__ int ws[4], wo[4];
    if (lane == 63) ws[wv] = v;
    __syncthreads();
    if (threadIdx.x == 0) {
        int run = 0;
        for (int w = 0; w < 4; ++w) { int tmp = ws[w]; wo[w] = run; run += tmp; }
    }
    __syncthreads();
    int excl = part[blockIdx.x] + wo[wv] + v - v0;
    if (i < NN) { rowptr[i] = excl; cursor[i] = excl; }
}

// ---------------- range-phased bucket-fill ----------------
// blockIdx = r*CPB + chunk, r major: co-resident blocks share one 12.5k-node
// dst range, so the active csr_src write region is ~800 KB (cache-resident)
// instead of 6.4 MB -> kills the 16x write amplification.
__global__ __launch_bounds__(256) void k_fillr(const int* __restrict__ src,
                                               const int* __restrict__ dst,
                                               int* __restrict__ cursor,
                                               int* __restrict__ csr_src) {
    int r = blockIdx.x / CPB;
    int chunk = blockIdx.x % CPB;
    int lo = r * RSZ, hi = lo + RSZ;   // [lo, hi)
    int base = chunk * EPB + threadIdx.x;
    #pragma unroll
    for (int i = 0; i < EPB / 256; ++i) {
        int e = base + i * 256;
        if (e < NE) {
            int d = dst[e];
            if (d >= lo && d < hi) {
                int p = atomicAdd(&cursor[d], 1);
                csr_src[p] = src[e];
            }
        }
    }
}

// ---------------- h1s = dinv * (x @ W1)  (N x 256 x 64) ----------------
__global__ __launch_bounds__(512) void k_gemm1(const float* __restrict__ x,
                                               const float* __restrict__ W1,
                                               const float* __restrict__ dinv,
                                               float* __restrict__ h1s) {
    __shared__ float xs[2][64 * 17];
    const int t = threadIdx.x;
    const int lane = t & 63;
    const int wvu = __builtin_amdgcn_readfirstlane(t >> 6);  // uniform wave id
    const int r0 = blockIdx.x * 64;
    const int sr = t >> 3;
    const int sk = (t & 7) * 2;
    const long xrow = (long)min(r0 + sr, NN - 1) * DI;
    const int row = r0 + lane;

    float acc[8] = {0.f, 0.f, 0.f, 0.f, 0.f, 0.f, 0.f, 0.f};

    {   // stage chunk 0
        float2 v = *(const float2*)(x + xrow + sk);
        xs[0][sr * 17 + sk] = v.x;
        xs[0][sr * 17 + sk + 1] = v.y;
    }
    __syncthreads();
    for (int c = 0; c < 16; ++c) {
        const int buf = c & 1;
        if (c + 1 < 16) {
            float2 v = *(const float2*)(x + xrow + (c + 1) * 16 + sk);
            xs[buf ^ 1][sr * 17 + sk] = v.x;
            xs[buf ^ 1][sr * 17 + sk + 1] = v.y;
        }
        const f8* wp = (const f8*)(W1) + (size_t)(c * 16) * (DH / 8) + wvu;
        #pragma unroll
        for (int k = 0; k < 16; ++k) {
            float xv = xs[buf][lane * 17 + k];
            f8 w8 = wp[(size_t)k * (DH / 8)];
            #pragma unroll
            for (int j = 0; j < 8; ++j) acc[j] += w8[j] * xv;
        }
        __syncthreads();
    }
    if (row < NN) {
        float di = dinv[row];
        float4 o0 = {di * acc[0], di * acc[1], di * acc[2], di * acc[3]};
        float4 o1 = {di * acc[4], di * acc[5], di * acc[6], di * acc[7]};
        float4* hp = (float4*)(h1s + (long)row * DH + wvu * 8);
        hp[0] = o0;
        hp[1] = o1;
    }
}

// ---------------- layer1 gather + relu/bias + GEMM2 fused ----------------
// agg = dinv[d]*(sum_s h1s[s] + h1s[d]); h2=relu(agg+b1); h3s = dinv[d]*(h2@W2)
__global__ __launch_bounds__(256) void k_agg1(const int* __restrict__ rowptr,
                                              const int* __restrict__ deg,
                                              const int* __restrict__ csr_src,
                                              const float* __restrict__ dinv,
                                              const float* __restrict__ h1s,
                                              const float* __restrict__ b1,
                                              const float* __restrict__ W2,
                                              float* __restrict__ h3s) {
    __shared__ float w2[DH * DO];   // 12 KB
    __shared__ float sh[4][DH];
    for (int i = threadIdx.x; i < DH * DO; i += 256) w2[i] = W2[i];
    __syncthreads();
    int wv = threadIdx.x >> 6, lane = threadIdx.x & 63;
    int row = blockIdx.x * 4 + wv;   // NN % 4 == 0
    int beg = rowptr[row], cnt = deg[row];
    float acc = 0.f;
    int j = 0;
    for (; j + 7 < cnt; j += 8) {
        int s0 = csr_src[beg + j + 0], s1 = csr_src[beg + j + 1];
        int s2 = csr_src[beg + j + 2], s3 = csr_src[beg + j + 3];
        int s4 = csr_src[beg + j + 4], s5 = csr_src[beg + j + 5];
        int s6 = csr_src[beg + j + 6], s7 = csr_src[beg + j + 7];
        float v0 = h1s[(long)s0 * DH + lane], v1 = h1s[(long)s1 * DH + lane];
        float v2 = h1s[(long)s2 * DH + lane], v3 = h1s[(long)s3 * DH + lane];
        float v4 = h1s[(long)s4 * DH + lane], v5 = h1s[(long)s5 * DH + lane];
        float v6 = h1s[(long)s6 * DH + lane], v7 = h1s[(long)s7 * DH + lane];
        acc += ((v0 + v1) + (v2 + v3)) + ((v4 + v5) + (v6 + v7));
    }
    for (; j < cnt; ++j) {
        int s = csr_src[beg + j];
        acc += h1s[(long)s * DH + lane];
    }
    float di = dinv[row];
    float v = di * (acc + h1s[(long)row * DH + lane]) + b1[lane];
    sh[wv][lane] = fmaxf(v, 0.f);
    __syncthreads();
    if (lane < DO) {
        float o = 0.f;
        #pragma unroll 8
        for (int k = 0; k < DH; ++k)
            o += sh[wv][k] * w2[k * DO + lane];
        h3s[(long)row * DH3 + lane] = di * o;
    }
}

// ---------------- layer2 gather + self-loop/bias + softmax/argmax fused ----------------
__global__ __launch_bounds__(256) void k_agg2(const int* __restrict__ rowptr,
                                              const int* __restrict__ deg,
                                              const int* __restrict__ csr_src,
                                              const float* __restrict__ dinv,
                                              const float* __restrict__ h3s,
                                              const float* __restrict__ b2,
                                              float* __restrict__ logits,
                                              float* __restrict__ preds,
                                              float* __restrict__ xo) {
    int wv = threadIdx.x >> 6, lane = threadIdx.x & 63;
    int row = blockIdx.x * 4 + wv;
    int beg = rowptr[row], cnt = deg[row];
    float acc = 0.f;
    bool act = lane < DO;
    int j = 0;
    for (; j + 7 < cnt; j += 8) {
        int s0 = csr_src[beg + j + 0], s1 = csr_src[beg + j + 1];
        int s2 = csr_src[beg + j + 2], s3 = csr_src[beg + j + 3];
        int s4 = csr_src[beg + j + 4], s5 = csr_src[beg + j + 5];
        int s6 = csr_src[beg + j + 6], s7 = csr_src[beg + j + 7];
        if (act) {
            float v0 = h3s[(long)s0 * DH3 + lane], v1 = h3s[(long)s1 * DH3 + lane];
            float v2 = h3s[(long)s2 * DH3 + lane], v3 = h3s[(long)s3 * DH3 + lane];
            float v4 = h3s[(long)s4 * DH3 + lane], v5 = h3s[(long)s5 * DH3 + lane];
            float v6 = h3s[(long)s6 * DH3 + lane], v7 = h3s[(long)s7 * DH3 + lane];
            acc += ((v0 + v1) + (v2 + v3)) + ((v4 + v5) + (v6 + v7));
        }
    }
    for (; j < cnt; ++j) {
        int s = csr_src[beg + j];
        if (act) acc += h3s[(long)s * DH3 + lane];
    }
    float di = dinv[row];
    float val = -INFINITY;
    if (act) {
        val = di * (acc + h3s[(long)row * DH3 + lane]) + b2[lane];
        xo[(long)row * DO + lane] = val;
    }
    float m = val;
    for (int off = 32; off; off >>= 1) m = fmaxf(m, __shfl_xor(m, off));
    int idx = (act && val == m) ? lane : (1 << 30);
    for (int off = 32; off; off >>= 1) idx = min(idx, __shfl_xor(idx, off));
    float ev = act ? expf(val - m) : 0.f;
    float ssum = ev;
    for (int off = 32; off; off >>= 1) ssum += __shfl_xor(ssum, off);
    if (act) logits[(long)row * DO + lane] = ev / ssum;
    if (lane == 0) preds[row] = (float)idx;
}

extern "C" void kernel_launch(void* const* d_in, const int* in_sizes, int n_in,
                              void* d_out, int out_size, void* d_ws, size_t ws_size,
                              hipStream_t stream) {
    const float* x  = (const float*)d_in[0];
    const int*   ei = (const int*)d_in[1];
    const float* W1 = (const float*)d_in[2];
    const float* b1 = (const float*)d_in[3];
    const float* W2 = (const float*)d_in[4];
    const float* b2 = (const float*)d_in[5];
    const int* src = ei;          // edge_index[0]
    const int* dst = ei + NE;     // edge_index[1]

    float* out    = (float*)d_out;
    float* logits = out;                      // [N,47]
    float* preds  = out + (long)NN * DO;      // [N]
    float* xo     = preds + NN;               // [N,47]

    // workspace layout
    char* wsb = (char*)d_ws;
    int*   deg     = (int*)wsb;                         wsb += (size_t)NN * 4;
    float* dinv    = (float*)wsb;                       wsb += (size_t)NN * 4;
    int*   rowptr  = (int*)wsb;                         wsb += (size_t)NN * 4;
    int*   cursor  = (int*)wsb;                         wsb += (size_t)NN * 4;
    int*   part    = (int*)wsb;                         wsb += (size_t)512 * 4;
    int*   csr_src = (int*)wsb;                         wsb += (size_t)NE * 4;
    float* h1s     = (float*)wsb;                       wsb += (size_t)NN * DH * 4;
    float* h3s     = (float*)wsb;                       wsb += (size_t)NN * DH3 * 4;

    hipMemsetAsync(deg, 0, NN * sizeof(int), stream);

    k_degree<<<(NE + 255) / 256, 256, 0, stream>>>(dst, deg);
    k_dinv<<<(NN + 255) / 256, 256, 0, stream>>>(deg, dinv);
    k_part<<<NB, 256, 0, stream>>>(deg, part);
    k_scanpart<<<1, 512, 0, stream>>>(part);
    k_scan3<<<NB, 256, 0, stream>>>(deg, part, rowptr, cursor);
    k_fillr<<<NRANGE * CPB, 256, 0, stream>>>(src, dst, cursor, csr_src);
    k_gemm1<<<(NN + 63) / 64, 512, 0, stream>>>(x, W1, dinv, h1s);
    k_agg1<<<NN / 4, 256, 0, stream>>>(rowptr, deg, csr_src, dinv, h1s, b1, W2, h3s);
    k_agg2<<<NN / 4, 256, 0, stream>>>(rowptr, deg, csr_src, dinv, h3s, b2, logits, preds, xo);
}